// Round 1
// baseline (997.297 us; speedup 1.0000x reference)
//
#include <hip/hip_runtime.h>
#include <math.h>

#define NB 32
#define NL 4096
#define ND 1024
#define NK 64

// ---------------- Kernel 1: logits[b,l,k] = feats[b,l,:] . W[k,:] + bias[k]
// grid: NB * NL/64 blocks, 256 threads. 64 rows x 64 cols per block.
__global__ __launch_bounds__(256) void k_logits(const float* __restrict__ feats,
                                                const float* __restrict__ W,
                                                const float* __restrict__ bias,
                                                float* __restrict__ logits) {
    __shared__ float As[64][68];  // rows = l, stride 68 (16B aligned, conflict-spread)
    __shared__ float Ws[64][68];  // rows = k
    const int t = threadIdx.x;
    const int bid = blockIdx.x;
    const int b = bid >> 6;            // 64 blocks per batch row
    const int l0 = (bid & 63) << 6;
    const int tx = t & 15;             // k fine index (k = tx + 16*j)
    const int ty = t >> 4;             // row group (rows ty*4 .. ty*4+3)
    const int r0 = ty * 4;

    float acc[4][4];
#pragma unroll
    for (int i = 0; i < 4; ++i)
#pragma unroll
        for (int j = 0; j < 4; ++j) acc[i][j] = 0.f;

    const size_t fbase = ((size_t)b * NL + l0) * ND;

    for (int dc = 0; dc < ND; dc += 64) {
#pragma unroll
        for (int p = 0; p < 4; ++p) {
            int e = p * 256 + t;
            int r = e >> 4;
            int c = (e & 15) << 2;
            *(float4*)&As[r][c] = *(const float4*)(feats + fbase + (size_t)r * ND + dc + c);
            *(float4*)&Ws[r][c] = *(const float4*)(W + (size_t)r * ND + dc + c);
        }
        __syncthreads();
#pragma unroll
        for (int d = 0; d < 64; d += 4) {
            float4 a0 = *(const float4*)&As[r0 + 0][d];
            float4 a1 = *(const float4*)&As[r0 + 1][d];
            float4 a2 = *(const float4*)&As[r0 + 2][d];
            float4 a3 = *(const float4*)&As[r0 + 3][d];
            float4 w0 = *(const float4*)&Ws[tx][d];
            float4 w1 = *(const float4*)&Ws[tx + 16][d];
            float4 w2 = *(const float4*)&Ws[tx + 32][d];
            float4 w3 = *(const float4*)&Ws[tx + 48][d];
#define STEP(comp) \
            acc[0][0] += a0.comp * w0.comp; acc[0][1] += a0.comp * w1.comp; \
            acc[0][2] += a0.comp * w2.comp; acc[0][3] += a0.comp * w3.comp; \
            acc[1][0] += a1.comp * w0.comp; acc[1][1] += a1.comp * w1.comp; \
            acc[1][2] += a1.comp * w2.comp; acc[1][3] += a1.comp * w3.comp; \
            acc[2][0] += a2.comp * w0.comp; acc[2][1] += a2.comp * w1.comp; \
            acc[2][2] += a2.comp * w2.comp; acc[2][3] += a2.comp * w3.comp; \
            acc[3][0] += a3.comp * w0.comp; acc[3][1] += a3.comp * w1.comp; \
            acc[3][2] += a3.comp * w2.comp; acc[3][3] += a3.comp * w3.comp;
            STEP(x) STEP(y) STEP(z) STEP(w)
#undef STEP
        }
        __syncthreads();
    }
#pragma unroll
    for (int i = 0; i < 4; ++i) {
        const int l = l0 + r0 + i;
        const size_t base = ((size_t)b * NL + l) * NK;
#pragma unroll
        for (int j = 0; j < 4; ++j) {
            const int k = tx + 16 * j;
            logits[base + k] = acc[i][j] + bias[k];
        }
    }
}

// ---------------- Kernel 2: per (b,k): m = max over valid l, s_inv = 1/sum exp
// grid: NB blocks, 256 threads (k = t&63, part = t>>6)
__global__ __launch_bounds__(256) void k_softmax_stats(const float* __restrict__ logits,
                                                       const int* __restrict__ lens,
                                                       float* __restrict__ mbuf,
                                                       float* __restrict__ sbuf) {
    const int b = blockIdx.x;
    const int t = threadIdx.x;
    const int k = t & 63;
    const int part = t >> 6;
    const int len = lens[b];
    const float* lg = logits + (size_t)b * NL * NK;

    float m = -1e30f;
    for (int l = part; l < len; l += 4) m = fmaxf(m, lg[(size_t)l * NK + k]);

    __shared__ float red[4][64];
    red[part][k] = m;
    __syncthreads();
    const float mf = fmaxf(fmaxf(red[0][k], red[1][k]), fmaxf(red[2][k], red[3][k]));

    float s = 0.f;
    for (int l = part; l < len; l += 4) s += __expf(lg[(size_t)l * NK + k] - mf);

    __syncthreads();
    red[part][k] = s;
    __syncthreads();
    if (t < 64) {
        const float sf = red[0][k] + red[1][k] + red[2][k] + red[3][k];
        mbuf[b * NK + k] = mf;
        sbuf[b * NK + k] = 1.0f / sf;
    }
}

// ---------------- Kernel 3: partial aggregation O[k,d] = sum_l a[l,k]*feats[l,d]
// grid: NB*2*8 (b, l-half, d-chunk of 128), 256 threads.
// thread (tk = t&15, td = t>>4) owns k in {tk,tk+16,tk+32,tk+48}, d in [td*8, td*8+8)
__global__ __launch_bounds__(256) void k_aggregate(const float* __restrict__ feats,
                                                   const float* __restrict__ logits,
                                                   const int* __restrict__ lens,
                                                   const float* __restrict__ mbuf,
                                                   const float* __restrict__ sbuf,
                                                   float* __restrict__ pO) {
    const int bid = blockIdx.x;
    const int b = bid >> 4;
    const int lhalf = (bid >> 3) & 1;
    const int dchunk = bid & 7;
    const int d0 = dchunk * 128;
    const int t = threadIdx.x;
    const int tk = t & 15;
    const int td = t >> 4;

    __shared__ float fs[32][132];
    __shared__ float as_[32][64];
    __shared__ float ms[64];
    __shared__ float is_[64];
    if (t < 64) { ms[t] = mbuf[b * NK + t]; is_[t] = sbuf[b * NK + t]; }
    const int len = lens[b];

    float acc[4][8];
#pragma unroll
    for (int j = 0; j < 4; ++j)
#pragma unroll
        for (int c = 0; c < 8; ++c) acc[j][c] = 0.f;

    const int lstart = lhalf * (NL / 2);
    const int lend = lstart + (NL / 2);

    for (int l0 = lstart; l0 < lend; l0 += 32) {
        __syncthreads();
        // stage feats tile [32][128]
#pragma unroll
        for (int p = 0; p < 4; ++p) {
            int e = p * 256 + t;
            int lt = e >> 5;
            int c = (e & 31) << 2;
            *(float4*)&fs[lt][c] =
                *(const float4*)(feats + ((size_t)b * NL + l0 + lt) * ND + d0 + c);
        }
        // stage a tile [32][64]
#pragma unroll
        for (int p = 0; p < 8; ++p) {
            int e = p * 256 + t;
            int lt = e >> 6;
            int kk = e & 63;
            int l = l0 + lt;
            float a = 0.f;
            if (l < len)
                a = __expf(logits[((size_t)b * NL + l) * NK + kk] - ms[kk]) * is_[kk];
            as_[lt][kk] = a;
        }
        __syncthreads();
#pragma unroll
        for (int lt = 0; lt < 32; ++lt) {
            const float a0 = as_[lt][tk];
            const float a1 = as_[lt][tk + 16];
            const float a2 = as_[lt][tk + 32];
            const float a3 = as_[lt][tk + 48];
            const float4 f0 = *(const float4*)&fs[lt][td * 8];
            const float4 f1 = *(const float4*)&fs[lt][td * 8 + 4];
#define AGG(j, av) \
            acc[j][0] += av * f0.x; acc[j][1] += av * f0.y; \
            acc[j][2] += av * f0.z; acc[j][3] += av * f0.w; \
            acc[j][4] += av * f1.x; acc[j][5] += av * f1.y; \
            acc[j][6] += av * f1.z; acc[j][7] += av * f1.w;
            AGG(0, a0) AGG(1, a1) AGG(2, a2) AGG(3, a3)
#undef AGG
        }
    }
    // write partial O: layout pO[(b*2+lhalf)*8 + dchunk][k][128]
    float* po = pO + ((size_t)((b * 2 + lhalf) * 8 + dchunk)) * NK * 128;
#pragma unroll
    for (int j = 0; j < 4; ++j) {
        const int k = tk + 16 * j;
        float4 v0 = make_float4(acc[j][0], acc[j][1], acc[j][2], acc[j][3]);
        float4 v1 = make_float4(acc[j][4], acc[j][5], acc[j][6], acc[j][7]);
        *(float4*)&po[k * 128 + td * 8] = v0;
        *(float4*)&po[k * 128 + td * 8 + 4] = v1;
    }
}

// ---------------- Kernel 3b: combine halves, subtract centroid, min over k
// grid: NB*8, 128 threads (one d each)
__global__ __launch_bounds__(128) void k_combine_min(const float* __restrict__ pO,
                                                     const float* __restrict__ centroids,
                                                     float* __restrict__ outun) {
    const int b = blockIdx.x >> 3;
    const int dchunk = blockIdx.x & 7;
    const int d0 = dchunk * 128;
    const int d = threadIdx.x;
    const float* p0 = pO + ((size_t)((b * 2 + 0) * 8 + dchunk)) * NK * 128;
    const float* p1 = pO + ((size_t)((b * 2 + 1) * 8 + dchunk)) * NK * 128;
    float mn = 1e30f;
#pragma unroll 4
    for (int k = 0; k < NK; ++k) {
        float v = p0[k * 128 + d] + p1[k * 128 + d] - centroids[(size_t)k * ND + d0 + d];
        mn = fminf(mn, v);
    }
    outun[(size_t)b * ND + d0 + d] = mn;
}

// ---------------- Kernel 4: L2-normalize each row
// grid: NB, 256 threads
__global__ __launch_bounds__(256) void k_norm(const float* __restrict__ outun,
                                              float* __restrict__ out) {
    const int b = blockIdx.x;
    const int t = threadIdx.x;
    float ss = 0.f;
    for (int d = t; d < ND; d += 256) {
        const float v = outun[(size_t)b * ND + d];
        ss += v * v;
    }
#pragma unroll
    for (int off = 32; off > 0; off >>= 1) ss += __shfl_down(ss, off);
    __shared__ float red[4];
    if ((t & 63) == 0) red[t >> 6] = ss;
    __syncthreads();
    const float tot = red[0] + red[1] + red[2] + red[3];
    const float inv = 1.0f / fmaxf(sqrtf(tot), 1e-12f);
    for (int d = t; d < ND; d += 256) out[(size_t)b * ND + d] = outun[(size_t)b * ND + d] * inv;
}

extern "C" void kernel_launch(void* const* d_in, const int* in_sizes, int n_in,
                              void* d_out, int out_size, void* d_ws, size_t ws_size,
                              hipStream_t stream) {
    const float* feats     = (const float*)d_in[0];
    const int*   lens      = (const int*)d_in[1];
    const float* W         = (const float*)d_in[2];
    const float* bias      = (const float*)d_in[3];
    const float* centroids = (const float*)d_in[4];
    float* out = (float*)d_out;

    char* ws = (char*)d_ws;
    float* logits = (float*)ws;                          // 32 MB
    size_t off = (size_t)NB * NL * NK * sizeof(float);
    float* mbuf = (float*)(ws + off); off += (size_t)NB * NK * sizeof(float);
    float* sbuf = (float*)(ws + off); off += (size_t)NB * NK * sizeof(float);
    float* outun = (float*)(ws + off); off += (size_t)NB * ND * sizeof(float);
    float* pO = (float*)(ws + off);                      // 16 MB

    k_logits<<<NB * (NL / 64), 256, 0, stream>>>(feats, W, bias, logits);
    k_softmax_stats<<<NB, 256, 0, stream>>>(logits, lens, mbuf, sbuf);
    k_aggregate<<<NB * 16, 256, 0, stream>>>(feats, logits, lens, mbuf, sbuf, pO);
    k_combine_min<<<NB * 8, 128, 0, stream>>>(pO, centroids, outun);
    k_norm<<<NB, 256, 0, stream>>>(outun, out);
}

// Round 2
// 602.193 us; speedup vs baseline: 1.6561x; 1.6561x over previous
//
#include <hip/hip_runtime.h>
#include <math.h>

#define NB 32
#define NL 4096
#define ND 1024
#define NK 64

typedef __bf16 bf16_t;
typedef __bf16 bf16x8 __attribute__((ext_vector_type(8)));
typedef __bf16 bf16x4 __attribute__((ext_vector_type(4)));
typedef float f32x4_t __attribute__((ext_vector_type(4)));

// ---------------- Kernel 0: W fp32 -> bf16 (128 KB, L2-resident afterwards)
__global__ __launch_bounds__(256) void k_convw(const float* __restrict__ W,
                                               bf16_t* __restrict__ Wb) {
    const int i = (blockIdx.x * 256 + threadIdx.x) * 4;
    const float4 v = *(const float4*)(W + i);
    bf16x4 o;
    o[0] = (bf16_t)v.x; o[1] = (bf16_t)v.y; o[2] = (bf16_t)v.z; o[3] = (bf16_t)v.w;
    *(bf16x4*)(Wb + i) = o;
}

// ---------------- Kernel 1: logits = feats . W^T + bias  (bf16 MFMA, no LDS)
// grid: NB * NL/64 = 2048 blocks, 256 thr / 4 waves. Block: 64 l x 64 k.
// Wave w owns m-tile (16 l). A-frag: 8 contiguous d fp32->bf16. B: Wb row, 16B.
__global__ __launch_bounds__(256) void k_logits(const float* __restrict__ feats,
                                                const bf16_t* __restrict__ Wb,
                                                const float* __restrict__ bias,
                                                const int* __restrict__ lens,
                                                float* __restrict__ logits) {
    const int bid = blockIdx.x;
    const int b = bid >> 6;
    const int l0 = (bid & 63) << 6;
    if (l0 >= lens[b]) return;   // rows >= len are never read downstream
    const int t = threadIdx.x;
    const int w = t >> 6;
    const int lane = t & 63;
    const int lr = lane & 15;    // m (or n) fine index
    const int oct = lane >> 4;   // contraction octet
    const float* fp = feats + ((size_t)b * NL + l0 + w * 16 + lr) * ND + oct * 8;

    f32x4_t acc[4];
#pragma unroll
    for (int j = 0; j < 4; ++j) acc[j] = (f32x4_t){0.f, 0.f, 0.f, 0.f};

#pragma unroll 4
    for (int kk = 0; kk < 32; ++kk) {
        const int d = kk * 32;
        const float4 a0 = *(const float4*)(fp + d);
        const float4 a1 = *(const float4*)(fp + d + 4);
        bf16x8 af;
        af[0] = (bf16_t)a0.x; af[1] = (bf16_t)a0.y; af[2] = (bf16_t)a0.z; af[3] = (bf16_t)a0.w;
        af[4] = (bf16_t)a1.x; af[5] = (bf16_t)a1.y; af[6] = (bf16_t)a1.z; af[7] = (bf16_t)a1.w;
#pragma unroll
        for (int j = 0; j < 4; ++j) {
            const bf16x8 bf = *(const bf16x8*)(Wb + (size_t)(j * 16 + lr) * ND + d + oct * 8);
            acc[j] = __builtin_amdgcn_mfma_f32_16x16x32_bf16(af, bf, acc[j], 0, 0, 0);
        }
    }
    // C layout: col(n)=lane&15, row(m)=oct*4+reg
#pragma unroll
    for (int j = 0; j < 4; ++j) {
        const int k = j * 16 + lr;
        const float bs = bias[k];
#pragma unroll
        for (int r = 0; r < 4; ++r) {
            const int l = l0 + w * 16 + oct * 4 + r;
            logits[((size_t)b * NL + l) * NK + k] = acc[j][r] + bs;
        }
    }
}

// ---------------- Kernel 2a: partial softmax stats per (b, 256-l chunk, k)
__global__ __launch_bounds__(256) void k_sm1(const float* __restrict__ logits,
                                             const int* __restrict__ lens,
                                             float* __restrict__ pmax,
                                             float* __restrict__ psum) {
    const int b = blockIdx.x >> 4;
    const int ch = blockIdx.x & 15;
    const int t = threadIdx.x;
    const int k = t & 63;
    const int part = t >> 6;
    const int lc0 = ch * 256;
    const int lend = min(lc0 + 256, lens[b]);
    const float* lg = logits + (size_t)b * NL * NK;

    float m = -1e30f;
    for (int l = lc0 + part; l < lend; l += 4) m = fmaxf(m, lg[(size_t)l * NK + k]);
    __shared__ float red[4][64];
    red[part][k] = m;
    __syncthreads();
    const float mf = fmaxf(fmaxf(red[0][k], red[1][k]), fmaxf(red[2][k], red[3][k]));
    float s = 0.f;
    for (int l = lc0 + part; l < lend; l += 4) s += __expf(lg[(size_t)l * NK + k] - mf);
    __syncthreads();
    red[part][k] = s;
    __syncthreads();
    if (t < 64) {
        psum[(b * 16 + ch) * 64 + k] = red[0][k] + red[1][k] + red[2][k] + red[3][k];
        pmax[(b * 16 + ch) * 64 + k] = mf;
    }
}

// ---------------- Kernel 2b: combine chunk stats -> m, 1/s per (b,k)
__global__ void k_sm2(const float* __restrict__ pmax, const float* __restrict__ psum,
                      float* __restrict__ mbuf, float* __restrict__ sbuf) {
    const int b = blockIdx.x;
    const int k = threadIdx.x;  // 64 threads
    float m = -1e30f;
#pragma unroll
    for (int c = 0; c < 16; ++c) m = fmaxf(m, pmax[(b * 16 + c) * 64 + k]);
    float s = 0.f;
#pragma unroll
    for (int c = 0; c < 16; ++c)
        s += psum[(b * 16 + c) * 64 + k] * __expf(pmax[(b * 16 + c) * 64 + k] - m);
    mbuf[b * 64 + k] = m;
    sbuf[b * 64 + k] = 1.0f / s;
}

// ---------------- Kernel 3: partial aggregation (fp32, occupancy-fixed)
// grid: NB*4*8 = 1024 (b, l-quarter, d-chunk of 128), 256 thr.
__global__ __launch_bounds__(256) void k_aggregate(const float* __restrict__ feats,
                                                   const float* __restrict__ logits,
                                                   const int* __restrict__ lens,
                                                   const float* __restrict__ mbuf,
                                                   const float* __restrict__ sbuf,
                                                   float* __restrict__ pO) {
    const int bid = blockIdx.x;
    const int b = bid >> 5;
    const int lq = (bid >> 3) & 3;
    const int dc = bid & 7;
    const int d0 = dc * 128;
    const int t = threadIdx.x;
    const int tk = t & 15;
    const int td = t >> 4;

    __shared__ float fs[32][132];
    __shared__ float as_[32][64];
    __shared__ float ms[64];
    __shared__ float is_[64];
    if (t < 64) { ms[t] = mbuf[b * 64 + t]; is_[t] = sbuf[b * 64 + t]; }
    const int len = lens[b];

    float acc[4][8];
#pragma unroll
    for (int j = 0; j < 4; ++j)
#pragma unroll
        for (int c = 0; c < 8; ++c) acc[j][c] = 0.f;

    const int lstart = lq * 1024;
    for (int l0 = lstart; l0 < lstart + 1024; l0 += 32) {
        if (l0 >= len) break;   // uniform per block
        __syncthreads();
#pragma unroll
        for (int p = 0; p < 4; ++p) {
            int e = p * 256 + t;
            int lt = e >> 5;
            int c = (e & 31) << 2;
            *(float4*)&fs[lt][c] =
                *(const float4*)(feats + ((size_t)b * NL + l0 + lt) * ND + d0 + c);
        }
#pragma unroll
        for (int p = 0; p < 8; ++p) {
            int e = p * 256 + t;
            int lt = e >> 6;
            int kk = e & 63;
            int l = l0 + lt;
            float a = 0.f;
            if (l < len)
                a = __expf(logits[((size_t)b * NL + l) * NK + kk] - ms[kk]) * is_[kk];
            as_[lt][kk] = a;
        }
        __syncthreads();
#pragma unroll
        for (int lt = 0; lt < 32; ++lt) {
            const float a0 = as_[lt][tk];
            const float a1 = as_[lt][tk + 16];
            const float a2 = as_[lt][tk + 32];
            const float a3 = as_[lt][tk + 48];
            const float4 f0 = *(const float4*)&fs[lt][td * 8];
            const float4 f1 = *(const float4*)&fs[lt][td * 8 + 4];
#define AGG(j, av) \
            acc[j][0] += av * f0.x; acc[j][1] += av * f0.y; \
            acc[j][2] += av * f0.z; acc[j][3] += av * f0.w; \
            acc[j][4] += av * f1.x; acc[j][5] += av * f1.y; \
            acc[j][6] += av * f1.z; acc[j][7] += av * f1.w;
            AGG(0, a0) AGG(1, a1) AGG(2, a2) AGG(3, a3)
#undef AGG
        }
    }
    float* po = pO + ((size_t)((b * 4 + lq) * 8 + dc)) * NK * 128;
#pragma unroll
    for (int j = 0; j < 4; ++j) {
        const int k = tk + 16 * j;
        float4 v0 = make_float4(acc[j][0], acc[j][1], acc[j][2], acc[j][3]);
        float4 v1 = make_float4(acc[j][4], acc[j][5], acc[j][6], acc[j][7]);
        *(float4*)&po[k * 128 + td * 8] = v0;
        *(float4*)&po[k * 128 + td * 8 + 4] = v1;
    }
}

// ---------------- Kernel 4: combine 4 partials, subtract centroid, min over k
__global__ __launch_bounds__(128) void k_combine(const float* __restrict__ pO,
                                                 const float* __restrict__ centroids,
                                                 float* __restrict__ outun) {
    const int b = blockIdx.x >> 3;
    const int dc = blockIdx.x & 7;
    const int d0 = dc * 128;
    const int d = threadIdx.x;
    const float* p0 = pO + ((size_t)((b * 4 + 0) * 8 + dc)) * NK * 128;
    const size_t qs = (size_t)8 * NK * 128;  // stride between l-quarters
    float mn = 1e30f;
#pragma unroll 4
    for (int k = 0; k < NK; ++k) {
        float v = p0[k * 128 + d] + p0[qs + k * 128 + d] + p0[2 * qs + k * 128 + d] +
                  p0[3 * qs + k * 128 + d] - centroids[(size_t)k * ND + d0 + d];
        mn = fminf(mn, v);
    }
    outun[(size_t)b * ND + d0 + d] = mn;
}

// ---------------- Kernel 5: L2-normalize rows
__global__ __launch_bounds__(256) void k_norm(const float* __restrict__ outun,
                                              float* __restrict__ out) {
    const int b = blockIdx.x;
    const int t = threadIdx.x;
    float ss = 0.f;
    for (int d = t; d < ND; d += 256) {
        const float v = outun[(size_t)b * ND + d];
        ss += v * v;
    }
#pragma unroll
    for (int off = 32; off > 0; off >>= 1) ss += __shfl_down(ss, off);
    __shared__ float red[4];
    if ((t & 63) == 0) red[t >> 6] = ss;
    __syncthreads();
    const float tot = red[0] + red[1] + red[2] + red[3];
    const float inv = 1.0f / fmaxf(sqrtf(tot), 1e-12f);
    for (int d = t; d < ND; d += 256) out[(size_t)b * ND + d] = outun[(size_t)b * ND + d] * inv;
}

extern "C" void kernel_launch(void* const* d_in, const int* in_sizes, int n_in,
                              void* d_out, int out_size, void* d_ws, size_t ws_size,
                              hipStream_t stream) {
    const float* feats     = (const float*)d_in[0];
    const int*   lens      = (const int*)d_in[1];
    const float* W         = (const float*)d_in[2];
    const float* bias      = (const float*)d_in[3];
    const float* centroids = (const float*)d_in[4];
    float* out = (float*)d_out;

    char* ws = (char*)d_ws;
    size_t off = 0;
    bf16_t* Wb   = (bf16_t*)(ws + off); off += (size_t)NK * ND * sizeof(bf16_t);   // 128 KB
    float* logits = (float*)(ws + off); off += (size_t)NB * NL * NK * sizeof(float); // 32 MB
    float* pmax  = (float*)(ws + off);  off += (size_t)NB * 16 * NK * sizeof(float);
    float* psum  = (float*)(ws + off);  off += (size_t)NB * 16 * NK * sizeof(float);
    float* mbuf  = (float*)(ws + off);  off += (size_t)NB * NK * sizeof(float);
    float* sbuf  = (float*)(ws + off);  off += (size_t)NB * NK * sizeof(float);
    float* outun = (float*)(ws + off);  off += (size_t)NB * ND * sizeof(float);
    float* pO    = (float*)(ws + off);  // 32 MB

    k_convw<<<NK * ND / 1024, 256, 0, stream>>>(W, Wb);
    k_logits<<<NB * (NL / 64), 256, 0, stream>>>(feats, Wb, bias, lens, logits);
    k_sm1<<<NB * 16, 256, 0, stream>>>(logits, lens, pmax, psum);
    k_sm2<<<NB, 64, 0, stream>>>(pmax, psum, mbuf, sbuf);
    k_aggregate<<<NB * 32, 256, 0, stream>>>(feats, logits, lens, mbuf, sbuf, pO);
    k_combine<<<NB * 8, 128, 0, stream>>>(pO, centroids, outun);
    k_norm<<<NB, 256, 0, stream>>>(outun, out);
}

// Round 5
// 444.029 us; speedup vs baseline: 2.2460x; 1.3562x over previous
//
#include <hip/hip_runtime.h>
#include <math.h>

#define NB 32
#define NL 4096
#define ND 1024
#define NK 64
#define DTILE 128
#define S_SPLIT 4

typedef __bf16 bf16_t;
typedef __bf16 bf16x8 __attribute__((ext_vector_type(8)));
typedef __bf16 bf16x4 __attribute__((ext_vector_type(4)));
typedef float f32x4_t __attribute__((ext_vector_type(4)));

// ---------------- Kernel 0: W fp32 -> bf16
__global__ __launch_bounds__(256) void k_convw(const float* __restrict__ W,
                                               bf16_t* __restrict__ Wb) {
    const int i = (blockIdx.x * 256 + threadIdx.x) * 4;
    const float4 v = *(const float4*)(W + i);
    bf16x4 o;
    o[0] = (bf16_t)v.x; o[1] = (bf16_t)v.y; o[2] = (bf16_t)v.z; o[3] = (bf16_t)v.w;
    *(bf16x4*)(Wb + i) = o;
}

// ---------------- Kernel 1: logits (bf16 MFMA) + fused per-chunk softmax stats
// Verified convention (round 2 PASS): A lane(lr,oct): m=lr, c=oct*8+j;
// B lane(lr,oct): n=lr, c=oct*8+j; C: col(n)=lane&15, row(m)=oct*4+reg.
__global__ __launch_bounds__(256) void k_logits(const float* __restrict__ feats,
                                                const bf16_t* __restrict__ Wb,
                                                const float* __restrict__ bias,
                                                const int* __restrict__ lens,
                                                float* __restrict__ logits,
                                                float* __restrict__ pmax,
                                                float* __restrict__ psum) {
    const int bid = blockIdx.x;
    const int b = bid >> 6;
    const int chunk = bid & 63;
    const int l0 = chunk << 6;
    const int len = lens[b];
    if (l0 >= len) return;   // rows >= len never read downstream
    const int t = threadIdx.x;
    const int w = t >> 6;
    const int lane = t & 63;
    const int lr = lane & 15;
    const int oct = lane >> 4;
    const float* fp = feats + ((size_t)b * NL + l0 + w * 16 + lr) * ND + oct * 8;

    f32x4_t acc[4];
#pragma unroll
    for (int j = 0; j < 4; ++j) acc[j] = (f32x4_t){0.f, 0.f, 0.f, 0.f};

#pragma unroll 4
    for (int kk = 0; kk < 32; ++kk) {
        const int d = kk * 32;
        const float4 a0 = *(const float4*)(fp + d);
        const float4 a1 = *(const float4*)(fp + d + 4);
        bf16x8 af;
        af[0] = (bf16_t)a0.x; af[1] = (bf16_t)a0.y; af[2] = (bf16_t)a0.z; af[3] = (bf16_t)a0.w;
        af[4] = (bf16_t)a1.x; af[5] = (bf16_t)a1.y; af[6] = (bf16_t)a1.z; af[7] = (bf16_t)a1.w;
#pragma unroll
        for (int j = 0; j < 4; ++j) {
            const bf16x8 bf = *(const bf16x8*)(Wb + (size_t)(j * 16 + lr) * ND + d + oct * 8);
            acc[j] = __builtin_amdgcn_mfma_f32_16x16x32_bf16(af, bf, acc[j], 0, 0, 0);
        }
    }
    float vals[4][4];
#pragma unroll
    for (int j = 0; j < 4; ++j) {
        const int k = j * 16 + lr;
        const float bs = bias[k];
#pragma unroll
        for (int r = 0; r < 4; ++r) {
            const int l = l0 + w * 16 + oct * 4 + r;
            vals[j][r] = acc[j][r] + bs;
            logits[((size_t)b * NL + l) * NK + k] = vals[j][r];
        }
    }
    // fused partial softmax stats for this 64-l chunk
    __shared__ float red[64][17];
    __shared__ float bm[64];
    const int slot = w * 4 + oct;
    const int lbase = l0 + w * 16 + oct * 4;
#pragma unroll
    for (int j = 0; j < 4; ++j) {
        float vm = -1e30f;
#pragma unroll
        for (int r = 0; r < 4; ++r)
            if (lbase + r < len) vm = fmaxf(vm, vals[j][r]);
        red[j * 16 + lr][slot] = vm;
    }
    __syncthreads();
    if (t < 64) {
        float m = -1e30f;
#pragma unroll
        for (int q = 0; q < 16; ++q) m = fmaxf(m, red[t][q]);
        bm[t] = m;
    }
    __syncthreads();
#pragma unroll
    for (int j = 0; j < 4; ++j) {
        const float mk = bm[j * 16 + lr];
        float sj = 0.f;
#pragma unroll
        for (int r = 0; r < 4; ++r)
            if (lbase + r < len) sj += __expf(vals[j][r] - mk);
        red[j * 16 + lr][slot] = sj;
    }
    __syncthreads();
    if (t < 64) {
        float ssum = 0.f;
#pragma unroll
        for (int q = 0; q < 16; ++q) ssum += red[t][q];
        pmax[((size_t)b * 64 + chunk) * 64 + t] = bm[t];
        psum[((size_t)b * 64 + chunk) * 64 + t] = ssum;
    }
}

// ---------------- Kernel 2: combine chunk stats -> mbuf2 = m + ln(s) per (b,k)
__global__ void k_sm2(const float* __restrict__ pmax, const float* __restrict__ psum,
                      const int* __restrict__ lens,
                      float* __restrict__ mbuf2) {
    const int b = blockIdx.x;
    const int k = threadIdx.x;  // 64 threads
    const int nc = (lens[b] + 63) >> 6;
    float m = -1e30f;
    for (int c = 0; c < nc; ++c) m = fmaxf(m, pmax[((size_t)b * 64 + c) * 64 + k]);
    float s = 0.f;
    for (int c = 0; c < nc; ++c)
        s += psum[((size_t)b * 64 + c) * 64 + k] * __expf(pmax[((size_t)b * 64 + c) * 64 + k] - m);
    mbuf2[b * 64 + k] = m + logf(s);
}

// ---------------- Kernel 3: compensated bf16-MFMA aggregation, explicit LDS transpose
// O[k,d] = sum_l a[l,k]*f[l,d]. LDS holds aT[64k][64l], fT[128d][64l] (hi/lo),
// chunk-XOR swizzled: byte(row,l) = row*128 + (((l>>3) ^ ((row^(row>>3))&7))<<4) + (l&7)*2.
// Fragments are plain ds_read_b128 of 8 contraction-contiguous l (no tr_read).
__global__ __launch_bounds__(256) void k_aggregate(const float* __restrict__ feats,
                                                   const float* __restrict__ logits,
                                                   const int* __restrict__ lens,
                                                   const float* __restrict__ mbuf2,
                                                   float* __restrict__ pO) {
    const int bid = blockIdx.x;
    const int s  = bid & 3;
    const int dc = (bid >> 2) & 7;
    const int b  = bid >> 5;
    const int d0 = dc * DTILE;
    const int t = threadIdx.x;
    const int w = t >> 6;
    const int lane = t & 63;
    const int lr = lane & 15;
    const int oct = lane >> 4;
    const int len = lens[b];
    const int nT = (len + 63) >> 6;
    const int t0 = (nT * s) >> 2;
    const int t1 = (nT * (s + 1)) >> 2;

    __shared__ uint4 lds4[48 * 1024 / 16];   // 48 KB
    char* const ldsb = (char*)&lds4[0];
    char* const aH = ldsb;                 // 8 KB
    char* const aL = ldsb + 8 * 1024;      // 8 KB
    char* const fH = ldsb + 16 * 1024;     // 16 KB
    char* const fL = ldsb + 32 * 1024;     // 16 KB

    // a-staging constants: this thread owns k=ka, rows la0+{0..3} per phase
    const int ka = t & 63;
    const int la0 = (t >> 6) * 4;
    const float ms2 = mbuf2[b * 64 + ka];
    const int aswz = (ka ^ (ka >> 3)) & 7;

    // f-staging constants
    const int c4 = (t & 31) * 4;
    const int lf0 = (t >> 5) * 4;

    f32x4_t acc[8];
#pragma unroll
    for (int n = 0; n < 8; ++n) acc[n] = (f32x4_t){0.f, 0.f, 0.f, 0.f};

    for (int tile = t0; tile < t1; ++tile) {
        const int l0 = tile * 64;
        __syncthreads();
        // ---- stage a^T (hi/lo): 64l x 64k
#pragma unroll
        for (int p = 0; p < 4; ++p) {
            const int l4 = p * 16 + la0;
            float av[4];
#pragma unroll
            for (int i = 0; i < 4; ++i) {
                const int l = l0 + l4 + i;
                const float lg = logits[((size_t)b * NL + l) * NK + ka];
                av[i] = (l < len) ? __expf(lg - ms2) : 0.f;
            }
            bf16x4 hi, lo;
#pragma unroll
            for (int i = 0; i < 4; ++i) {
                hi[i] = (bf16_t)av[i];
                lo[i] = (bf16_t)(av[i] - (float)hi[i]);
            }
            const int chunk = (l4 >> 3) ^ aswz;
            const int off = ka * 128 + (chunk << 4) + (l4 & 7) * 2;
            *(bf16x4*)(aH + off) = hi;
            *(bf16x4*)(aL + off) = lo;
        }
        // ---- stage f^T (hi/lo): 64l x 128d, 4x4 register micro-transpose
#pragma unroll
        for (int p = 0; p < 2; ++p) {
            const int l4 = p * 32 + lf0;
            float rc[4][4];
#pragma unroll
            for (int i = 0; i < 4; ++i) {
                const float4 r =
                    *(const float4*)(feats + ((size_t)b * NL + l0 + l4 + i) * ND + d0 + c4);
                rc[i][0] = r.x; rc[i][1] = r.y; rc[i][2] = r.z; rc[i][3] = r.w;
            }
#pragma unroll
            for (int j = 0; j < 4; ++j) {
                const int d = c4 + j;
                bf16x4 hi, lo;
#pragma unroll
                for (int i = 0; i < 4; ++i) {
                    hi[i] = (bf16_t)rc[i][j];
                    lo[i] = (bf16_t)(rc[i][j] - (float)hi[i]);
                }
                const int chunk = (l4 >> 3) ^ ((d ^ (d >> 3)) & 7);
                const int off = d * 128 + (chunk << 4) + (l4 & 7) * 2;
                *(bf16x4*)(fH + off) = hi;
                *(bf16x4*)(fL + off) = lo;
            }
        }
        __syncthreads();
        // ---- MFMA: wave w owns k in [w*16, w*16+16); 8 n-tiles of d
        const int kk = w * 16 + lr;
        const int kswz = (kk ^ (kk >> 3)) & 7;
#pragma unroll
        for (int ks = 0; ks < 2; ++ks) {
            const int cbase = ks * 4 + oct;  // chunk of contraction l = ks*32 + oct*8
            const int aoff = kk * 128 + ((cbase ^ kswz) << 4);
            const bf16x8 afH = *(const bf16x8*)(aH + aoff);
            const bf16x8 afL = *(const bf16x8*)(aL + aoff);
#pragma unroll
            for (int n = 0; n < 8; ++n) {
                const int d = n * 16 + lr;
                const int foff = d * 128 + ((cbase ^ ((d ^ (d >> 3)) & 7)) << 4);
                const bf16x8 bfH = *(const bf16x8*)(fH + foff);
                const bf16x8 bfL = *(const bf16x8*)(fL + foff);
                acc[n] = __builtin_amdgcn_mfma_f32_16x16x32_bf16(afH, bfH, acc[n], 0, 0, 0);
                acc[n] = __builtin_amdgcn_mfma_f32_16x16x32_bf16(afH, bfL, acc[n], 0, 0, 0);
                acc[n] = __builtin_amdgcn_mfma_f32_16x16x32_bf16(afL, bfH, acc[n], 0, 0, 0);
            }
        }
    }
    // write fp32 partials: pO[b][dc][s][k][DTILE]; C: row(m=k)=oct*4+r, col(n-tile d)=lr
    float* po = pO + ((size_t)((b * 8 + dc) * S_SPLIT + s)) * (NK * DTILE);
#pragma unroll
    for (int n = 0; n < 8; ++n) {
#pragma unroll
        for (int r = 0; r < 4; ++r) {
            const int k = w * 16 + oct * 4 + r;
            po[k * DTILE + n * 16 + lr] = acc[n][r];
        }
    }
}

// ---------------- Kernel 4: sum S_SPLIT partials, subtract centroid, min over k
__global__ __launch_bounds__(128) void k_combine(const float* __restrict__ pO,
                                                 const float* __restrict__ centroids,
                                                 float* __restrict__ outun) {
    const int b = blockIdx.x >> 3;
    const int d = (blockIdx.x & 7) * 128 + threadIdx.x;  // 0..1023
    const int dc = d >> 7;
    const int dl = d & 127;
    const float* base = pO + ((size_t)(b * 8 + dc)) * S_SPLIT * NK * DTILE;
    float mn = 1e30f;
    for (int k = 0; k < NK; ++k) {
        float v = 0.f;
#pragma unroll
        for (int s = 0; s < S_SPLIT; ++s) v += base[(size_t)(s * NK + k) * DTILE + dl];
        v -= centroids[(size_t)k * ND + d];
        mn = fminf(mn, v);
    }
    outun[(size_t)b * ND + d] = mn;
}

// ---------------- Kernel 5: L2-normalize rows
__global__ __launch_bounds__(256) void k_norm(const float* __restrict__ outun,
                                              float* __restrict__ out) {
    const int b = blockIdx.x;
    const int t = threadIdx.x;
    float ss = 0.f;
    for (int d = t; d < ND; d += 256) {
        const float v = outun[(size_t)b * ND + d];
        ss += v * v;
    }
#pragma unroll
    for (int off = 32; off > 0; off >>= 1) ss += __shfl_down(ss, off);
    __shared__ float red[4];
    if ((t & 63) == 0) red[t >> 6] = ss;
    __syncthreads();
    const float tot = red[0] + red[1] + red[2] + red[3];
    const float inv = 1.0f / fmaxf(sqrtf(tot), 1e-12f);
    for (int d = t; d < ND; d += 256) out[(size_t)b * ND + d] = outun[(size_t)b * ND + d] * inv;
}

extern "C" void kernel_launch(void* const* d_in, const int* in_sizes, int n_in,
                              void* d_out, int out_size, void* d_ws, size_t ws_size,
                              hipStream_t stream) {
    const float* feats     = (const float*)d_in[0];
    const int*   lens      = (const int*)d_in[1];
    const float* W         = (const float*)d_in[2];
    const float* bias      = (const float*)d_in[3];
    const float* centroids = (const float*)d_in[4];
    float* out = (float*)d_out;

    char* ws = (char*)d_ws;
    size_t off = 0;
    bf16_t* Wb    = (bf16_t*)(ws + off); off += (size_t)NK * ND * sizeof(bf16_t);
    float* logits = (float*)(ws + off);  off += (size_t)NB * NL * NK * sizeof(float);
    float* pmax   = (float*)(ws + off);  off += (size_t)NB * 64 * NK * sizeof(float);
    float* psum   = (float*)(ws + off);  off += (size_t)NB * 64 * NK * sizeof(float);
    float* mbuf2  = (float*)(ws + off);  off += (size_t)NB * NK * sizeof(float);
    float* outun  = (float*)(ws + off);  off += (size_t)NB * ND * sizeof(float);
    float* pO     = (float*)(ws + off);  // 32*8*4*64*128*4 = 33.6 MB

    k_convw<<<NK * ND / 1024, 256, 0, stream>>>(W, Wb);
    k_logits<<<NB * (NL / 64), 256, 0, stream>>>(feats, Wb, bias, lens, logits, pmax, psum);
    k_sm2<<<NB, 64, 0, stream>>>(pmax, psum, lens, mbuf2);
    k_aggregate<<<NB * 8 * S_SPLIT, 256, 0, stream>>>(feats, logits, lens, mbuf2, pO);
    k_combine<<<NB * 8, 128, 0, stream>>>(pO, centroids, outun);
    k_norm<<<NB, 256, 0, stream>>>(outun, out);
}

// Round 6
// 351.770 us; speedup vs baseline: 2.8351x; 1.2623x over previous
//
#include <hip/hip_runtime.h>
#include <math.h>

#define NB 32
#define NL 4096
#define ND 1024
#define NK 64
#define DTILE 128
#define S_SPLIT 4

typedef __bf16 bf16_t;
typedef __bf16 bf16x8 __attribute__((ext_vector_type(8)));
typedef __bf16 bf16x4 __attribute__((ext_vector_type(4)));
typedef float f32x4_t __attribute__((ext_vector_type(4)));

// ---------------- Kernel 0: W fp32 -> bf16
__global__ __launch_bounds__(256) void k_convw(const float* __restrict__ W,
                                               bf16_t* __restrict__ Wb) {
    const int i = (blockIdx.x * 256 + threadIdx.x) * 4;
    const float4 v = *(const float4*)(W + i);
    bf16x4 o;
    o[0] = (bf16_t)v.x; o[1] = (bf16_t)v.y; o[2] = (bf16_t)v.z; o[3] = (bf16_t)v.w;
    *(bf16x4*)(Wb + i) = o;
}

// ---------------- Kernel 1: logits (bf16 MFMA) + fused per-chunk softmax stats
// Writes logitsT[b][k][l] (transposed) with float4 stores.
__global__ __launch_bounds__(256) void k_logits(const float* __restrict__ feats,
                                                const bf16_t* __restrict__ Wb,
                                                const float* __restrict__ bias,
                                                const int* __restrict__ lens,
                                                float* __restrict__ logitsT,
                                                float* __restrict__ pmax,
                                                float* __restrict__ psum) {
    const int bid = blockIdx.x;
    const int b = bid >> 6;
    const int chunk = bid & 63;
    const int l0 = chunk << 6;
    const int len = lens[b];
    if (l0 >= len) return;   // rows >= len never read downstream
    const int t = threadIdx.x;
    const int w = t >> 6;
    const int lane = t & 63;
    const int lr = lane & 15;
    const int oct = lane >> 4;
    const float* fp = feats + ((size_t)b * NL + l0 + w * 16 + lr) * ND + oct * 8;

    f32x4_t acc[4];
#pragma unroll
    for (int j = 0; j < 4; ++j) acc[j] = (f32x4_t){0.f, 0.f, 0.f, 0.f};

#pragma unroll 4
    for (int kk = 0; kk < 32; ++kk) {
        const int d = kk * 32;
        const float4 a0 = *(const float4*)(fp + d);
        const float4 a1 = *(const float4*)(fp + d + 4);
        bf16x8 af;
        af[0] = (bf16_t)a0.x; af[1] = (bf16_t)a0.y; af[2] = (bf16_t)a0.z; af[3] = (bf16_t)a0.w;
        af[4] = (bf16_t)a1.x; af[5] = (bf16_t)a1.y; af[6] = (bf16_t)a1.z; af[7] = (bf16_t)a1.w;
#pragma unroll
        for (int j = 0; j < 4; ++j) {
            const bf16x8 bf = *(const bf16x8*)(Wb + (size_t)(j * 16 + lr) * ND + d + oct * 8);
            acc[j] = __builtin_amdgcn_mfma_f32_16x16x32_bf16(af, bf, acc[j], 0, 0, 0);
        }
    }
    // C layout: col(n)=lane&15 -> k, row(m)=oct*4+reg -> l
    float vals[4][4];
#pragma unroll
    for (int j = 0; j < 4; ++j) {
        const int k = j * 16 + lr;
        const float bs = bias[k];
#pragma unroll
        for (int r = 0; r < 4; ++r) vals[j][r] = acc[j][r] + bs;
        const int lb = l0 + w * 16 + oct * 4;
        float4 st = make_float4(vals[j][0], vals[j][1], vals[j][2], vals[j][3]);
        *(float4*)(logitsT + ((size_t)b * NK + k) * NL + lb) = st;
    }
    // fused partial softmax stats for this 64-l chunk
    __shared__ float red[64][17];
    __shared__ float bm[64];
    const int slot = w * 4 + oct;
    const int lbase = l0 + w * 16 + oct * 4;
#pragma unroll
    for (int j = 0; j < 4; ++j) {
        float vm = -1e30f;
#pragma unroll
        for (int r = 0; r < 4; ++r)
            if (lbase + r < len) vm = fmaxf(vm, vals[j][r]);
        red[j * 16 + lr][slot] = vm;
    }
    __syncthreads();
    if (t < 64) {
        float m = -1e30f;
#pragma unroll
        for (int q = 0; q < 16; ++q) m = fmaxf(m, red[t][q]);
        bm[t] = m;
    }
    __syncthreads();
#pragma unroll
    for (int j = 0; j < 4; ++j) {
        const float mk = bm[j * 16 + lr];
        float sj = 0.f;
#pragma unroll
        for (int r = 0; r < 4; ++r)
            if (lbase + r < len) sj += __expf(vals[j][r] - mk);
        red[j * 16 + lr][slot] = sj;
    }
    __syncthreads();
    if (t < 64) {
        float ssum = 0.f;
#pragma unroll
        for (int q = 0; q < 16; ++q) ssum += red[t][q];
        pmax[((size_t)b * 64 + chunk) * 64 + t] = bm[t];
        psum[((size_t)b * 64 + chunk) * 64 + t] = ssum;
    }
}

// ---------------- Kernel 2: combine chunk stats -> mbuf2 = m + ln(s) per (b,k)
__global__ void k_sm2(const float* __restrict__ pmax, const float* __restrict__ psum,
                      const int* __restrict__ lens,
                      float* __restrict__ mbuf2) {
    const int b = blockIdx.x;
    const int k = threadIdx.x;  // 64 threads
    const int nc = (lens[b] + 63) >> 6;
    float m = -1e30f;
    for (int c = 0; c < nc; ++c) m = fmaxf(m, pmax[((size_t)b * 64 + c) * 64 + k]);
    float s = 0.f;
    for (int c = 0; c < nc; ++c)
        s += psum[((size_t)b * 64 + c) * 64 + k] * __expf(pmax[((size_t)b * 64 + c) * 64 + k] - m);
    mbuf2[b * 64 + k] = m + logf(s);
}

// ---------------- Kernel 3: compensated bf16-MFMA aggregation
// a-fragments built directly in registers (per-lane exp of its own 16 (l,k));
// f transposed to LDS (hi/lo, chunk-XOR swizzle); T14 async prefetch of next tile.
__global__ __launch_bounds__(256, 4) void k_aggregate(const float* __restrict__ feats,
                                                      const float* __restrict__ logitsT,
                                                      const int* __restrict__ lens,
                                                      const float* __restrict__ mbuf2,
                                                      float* __restrict__ pO) {
    const int bid = blockIdx.x;
    const int s  = bid & 3;
    const int dc = (bid >> 2) & 7;
    const int b  = bid >> 5;
    const int d0 = dc * DTILE;
    const int t = threadIdx.x;
    const int w = t >> 6;
    const int lane = t & 63;
    const int lr = lane & 15;
    const int oct = lane >> 4;
    const int len = lens[b];
    const int nT = (len + 63) >> 6;
    const int t0 = (nT * s) >> 2;
    const int t1 = (nT * (s + 1)) >> 2;

    __shared__ char ldsb[32 * 1024];
    char* const fH = ldsb;                 // 16 KB
    char* const fL = ldsb + 16 * 1024;     // 16 KB

    const int kk = w * 16 + lr;                      // A m-row = k
    const float ms2k = mbuf2[b * 64 + kk];
    const float* lgrow = logitsT + ((size_t)b * NK + kk) * NL;

    // f-staging constants: thread owns rows lf0+{0..3} (x2 phases), cols c4..c4+3
    const int c4 = (t & 31) * 4;
    const int lf0 = (t >> 5) * 4;

    f32x4_t acc[8];
#pragma unroll
    for (int n = 0; n < 8; ++n) acc[n] = (f32x4_t){0.f, 0.f, 0.f, 0.f};

    float4 plg[4];       // [ks*2+h]: logits l-run for A frags
    float4 pf[2][4];     // [phase][row]: f rows

#define LOADT(tile_)                                                                     \
    {                                                                                    \
        const int lb_ = (tile_) * 64;                                                    \
        plg[0] = *(const float4*)(lgrow + lb_ + oct * 8);                                \
        plg[1] = *(const float4*)(lgrow + lb_ + oct * 8 + 4);                            \
        plg[2] = *(const float4*)(lgrow + lb_ + 32 + oct * 8);                           \
        plg[3] = *(const float4*)(lgrow + lb_ + 32 + oct * 8 + 4);                       \
        _Pragma("unroll")                                                                \
        for (int p_ = 0; p_ < 2; ++p_) {                                                 \
            _Pragma("unroll")                                                            \
            for (int i_ = 0; i_ < 4; ++i_)                                               \
                pf[p_][i_] = *(const float4*)(feats +                                    \
                    ((size_t)b * NL + lb_ + p_ * 32 + lf0 + i_) * ND + d0 + c4);         \
        }                                                                                \
    }

    if (t0 < t1) LOADT(t0);

    for (int tile = t0; tile < t1; ++tile) {
        const int l0 = tile * 64;
        // ---- build A fragments in registers from plg (current tile)
        bf16x8 afH[2], afL[2];
#pragma unroll
        for (int ks = 0; ks < 2; ++ks) {
#pragma unroll
            for (int h = 0; h < 2; ++h) {
                const float4 v = plg[ks * 2 + h];
                const int lbase = l0 + ks * 32 + oct * 8 + h * 4;
                float av[4];
                av[0] = (lbase + 0 < len) ? __expf(v.x - ms2k) : 0.f;
                av[1] = (lbase + 1 < len) ? __expf(v.y - ms2k) : 0.f;
                av[2] = (lbase + 2 < len) ? __expf(v.z - ms2k) : 0.f;
                av[3] = (lbase + 3 < len) ? __expf(v.w - ms2k) : 0.f;
#pragma unroll
                for (int c = 0; c < 4; ++c) {
                    const bf16_t hi = (bf16_t)av[c];
                    afH[ks][h * 4 + c] = hi;
                    afL[ks][h * 4 + c] = (bf16_t)(av[c] - (float)hi);
                }
            }
        }
        __syncthreads();   // all waves done reading fH/fL of previous tile
        // ---- stage f^T (hi/lo) from pf: 4x4 register micro-transpose
#pragma unroll
        for (int p = 0; p < 2; ++p) {
            const int l4 = p * 32 + lf0;
#pragma unroll
            for (int j = 0; j < 4; ++j) {
                const int d = c4 + j;
                bf16x4 hi, lo;
                const float e0 = (&pf[p][0].x)[j];
                const float e1 = (&pf[p][1].x)[j];
                const float e2 = (&pf[p][2].x)[j];
                const float e3 = (&pf[p][3].x)[j];
                hi[0] = (bf16_t)e0; hi[1] = (bf16_t)e1; hi[2] = (bf16_t)e2; hi[3] = (bf16_t)e3;
                lo[0] = (bf16_t)(e0 - (float)hi[0]); lo[1] = (bf16_t)(e1 - (float)hi[1]);
                lo[2] = (bf16_t)(e2 - (float)hi[2]); lo[3] = (bf16_t)(e3 - (float)hi[3]);
                const int chunk = (l4 >> 3) ^ ((d ^ (d >> 3)) & 7);
                const int off = d * 128 + (chunk << 4) + (l4 & 7) * 2;
                *(bf16x4*)(fH + off) = hi;
                *(bf16x4*)(fL + off) = lo;
            }
        }
        // ---- T14: issue next tile's global loads (in flight across barrier + MFMA)
        if (tile + 1 < t1) LOADT(tile + 1);
        __syncthreads();   // fH/fL ready
        // ---- MFMA: wave w owns k in [w*16, w*16+16); 8 n-tiles of d
#pragma unroll
        for (int ks = 0; ks < 2; ++ks) {
            const int cbase = ks * 4 + oct;  // chunk of contraction l = ks*32 + oct*8
#pragma unroll
            for (int n = 0; n < 8; ++n) {
                const int d = n * 16 + lr;
                const int foff = d * 128 + ((cbase ^ ((d ^ (d >> 3)) & 7)) << 4);
                const bf16x8 bfH = *(const bf16x8*)(fH + foff);
                const bf16x8 bfL = *(const bf16x8*)(fL + foff);
                acc[n] = __builtin_amdgcn_mfma_f32_16x16x32_bf16(afH[ks], bfH, acc[n], 0, 0, 0);
                acc[n] = __builtin_amdgcn_mfma_f32_16x16x32_bf16(afH[ks], bfL, acc[n], 0, 0, 0);
                acc[n] = __builtin_amdgcn_mfma_f32_16x16x32_bf16(afL[ks], bfH, acc[n], 0, 0, 0);
            }
        }
    }
#undef LOADT
    // write fp32 partials: pO[b][dc][s][k][DTILE]; C: row(m=k)=oct*4+r, col=lr
    float* po = pO + ((size_t)((b * 8 + dc) * S_SPLIT + s)) * (NK * DTILE);
#pragma unroll
    for (int n = 0; n < 8; ++n) {
#pragma unroll
        for (int r = 0; r < 4; ++r) {
            const int k = w * 16 + oct * 4 + r;
            po[k * DTILE + n * 16 + lr] = acc[n][r];
        }
    }
}

// ---------------- Kernel 4: sum S_SPLIT partials, subtract centroid, min over k
__global__ __launch_bounds__(128) void k_combine(const float* __restrict__ pO,
                                                 const float* __restrict__ centroids,
                                                 float* __restrict__ outun) {
    const int b = blockIdx.x >> 3;
    const int d = (blockIdx.x & 7) * 128 + threadIdx.x;  // 0..1023
    const int dc = d >> 7;
    const int dl = d & 127;
    const float* base = pO + ((size_t)(b * 8 + dc)) * S_SPLIT * NK * DTILE;
    float mn = 1e30f;
    for (int k = 0; k < NK; ++k) {
        float v = 0.f;
#pragma unroll
        for (int s = 0; s < S_SPLIT; ++s) v += base[(size_t)(s * NK + k) * DTILE + dl];
        v -= centroids[(size_t)k * ND + d];
        mn = fminf(mn, v);
    }
    outun[(size_t)b * ND + d] = mn;
}

// ---------------- Kernel 5: L2-normalize rows
__global__ __launch_bounds__(256) void k_norm(const float* __restrict__ outun,
                                              float* __restrict__ out) {
    const int b = blockIdx.x;
    const int t = threadIdx.x;
    float ss = 0.f;
    for (int d = t; d < ND; d += 256) {
        const float v = outun[(size_t)b * ND + d];
        ss += v * v;
    }
#pragma unroll
    for (int off = 32; off > 0; off >>= 1) ss += __shfl_down(ss, off);
    __shared__ float red[4];
    if ((t & 63) == 0) red[t >> 6] = ss;
    __syncthreads();
    const float tot = red[0] + red[1] + red[2] + red[3];
    const float inv = 1.0f / fmaxf(sqrtf(tot), 1e-12f);
    for (int d = t; d < ND; d += 256) out[(size_t)b * ND + d] = outun[(size_t)b * ND + d] * inv;
}

extern "C" void kernel_launch(void* const* d_in, const int* in_sizes, int n_in,
                              void* d_out, int out_size, void* d_ws, size_t ws_size,
                              hipStream_t stream) {
    const float* feats     = (const float*)d_in[0];
    const int*   lens      = (const int*)d_in[1];
    const float* W         = (const float*)d_in[2];
    const float* bias      = (const float*)d_in[3];
    const float* centroids = (const float*)d_in[4];
    float* out = (float*)d_out;

    char* ws = (char*)d_ws;
    size_t off = 0;
    bf16_t* Wb     = (bf16_t*)(ws + off); off += (size_t)NK * ND * sizeof(bf16_t);
    float* logitsT = (float*)(ws + off);  off += (size_t)NB * NL * NK * sizeof(float);
    float* pmax    = (float*)(ws + off);  off += (size_t)NB * 64 * NK * sizeof(float);
    float* psum    = (float*)(ws + off);  off += (size_t)NB * 64 * NK * sizeof(float);
    float* mbuf2   = (float*)(ws + off);  off += (size_t)NB * NK * sizeof(float);
    float* outun   = (float*)(ws + off);  off += (size_t)NB * ND * sizeof(float);
    float* pO      = (float*)(ws + off);  // 32*8*4*64*128*4 = 33.6 MB

    k_convw<<<NK * ND / 1024, 256, 0, stream>>>(W, Wb);
    k_logits<<<NB * (NL / 64), 256, 0, stream>>>(feats, Wb, bias, lens, logitsT, pmax, psum);
    k_sm2<<<NB, 64, 0, stream>>>(pmax, psum, lens, mbuf2);
    k_aggregate<<<NB * 8 * S_SPLIT, 256, 0, stream>>>(feats, logitsT, lens, mbuf2, pO);
    k_combine<<<NB * 8, 128, 0, stream>>>(pO, centroids, outun);
    k_norm<<<NB, 256, 0, stream>>>(outun, out);
}

// Round 7
// 284.560 us; speedup vs baseline: 3.5047x; 1.2362x over previous
//
#include <hip/hip_runtime.h>
#include <math.h>

#define NB 32
#define NL 4096
#define ND 1024
#define NK 64
#define DTILE 128
#define S_SPLIT 4

typedef __bf16 bf16_t;
typedef __bf16 bf16x8 __attribute__((ext_vector_type(8)));
typedef __bf16 bf16x4 __attribute__((ext_vector_type(4)));
typedef float f32x4_t __attribute__((ext_vector_type(4)));

// ---------------- Kernel 0: W fp32 -> bf16
__global__ __launch_bounds__(256) void k_convw(const float* __restrict__ W,
                                               bf16_t* __restrict__ Wb) {
    const int i = (blockIdx.x * 256 + threadIdx.x) * 4;
    const float4 v = *(const float4*)(W + i);
    bf16x4 o;
    o[0] = (bf16_t)v.x; o[1] = (bf16_t)v.y; o[2] = (bf16_t)v.z; o[3] = (bf16_t)v.w;
    *(bf16x4*)(Wb + i) = o;
}

// ---------------- Kernel 1: logits (bf16 MFMA), 128 l per block, fused stats
// Writes logitsT[b][k][l] with float4 stores.
// Verified conv: A lane(lr,oct): m=lr, c=oct*8+j; B: n=lr, c=oct*8+j;
// C: col(n)=lane&15, row(m)=oct*4+reg.
__global__ __launch_bounds__(256) void k_logits(const float* __restrict__ feats,
                                                const bf16_t* __restrict__ Wb,
                                                const float* __restrict__ bias,
                                                const int* __restrict__ lens,
                                                float* __restrict__ logitsT,
                                                float* __restrict__ pmax,
                                                float* __restrict__ psum) {
    const int bid = blockIdx.x;
    const int b = bid >> 5;
    const int chunk = bid & 31;
    const int l0 = chunk << 7;
    const int len = lens[b];
    if (l0 >= len) return;   // rows >= len never read downstream
    const int t = threadIdx.x;
    const int w = t >> 6;
    const int lane = t & 63;
    const int lr = lane & 15;
    const int oct = lane >> 4;
    // wave w owns rows [l0 + w*32, +32): m-tiles mt=0,1
    const float* fp0 = feats + ((size_t)b * NL + l0 + w * 32 + lr) * ND + oct * 8;
    const float* fp1 = fp0 + (size_t)16 * ND;

    f32x4_t acc[2][4];
#pragma unroll
    for (int m = 0; m < 2; ++m)
#pragma unroll
        for (int j = 0; j < 4; ++j) acc[m][j] = (f32x4_t){0.f, 0.f, 0.f, 0.f};

#pragma unroll 2
    for (int kk = 0; kk < 32; ++kk) {
        const int d = kk * 32;
        const float4 a0 = *(const float4*)(fp0 + d);
        const float4 a1 = *(const float4*)(fp0 + d + 4);
        const float4 a2 = *(const float4*)(fp1 + d);
        const float4 a3 = *(const float4*)(fp1 + d + 4);
        bf16x8 af0, af1;
        af0[0] = (bf16_t)a0.x; af0[1] = (bf16_t)a0.y; af0[2] = (bf16_t)a0.z; af0[3] = (bf16_t)a0.w;
        af0[4] = (bf16_t)a1.x; af0[5] = (bf16_t)a1.y; af0[6] = (bf16_t)a1.z; af0[7] = (bf16_t)a1.w;
        af1[0] = (bf16_t)a2.x; af1[1] = (bf16_t)a2.y; af1[2] = (bf16_t)a2.z; af1[3] = (bf16_t)a2.w;
        af1[4] = (bf16_t)a3.x; af1[5] = (bf16_t)a3.y; af1[6] = (bf16_t)a3.z; af1[7] = (bf16_t)a3.w;
#pragma unroll
        for (int j = 0; j < 4; ++j) {
            const bf16x8 bf = *(const bf16x8*)(Wb + (size_t)(j * 16 + lr) * ND + d + oct * 8);
            acc[0][j] = __builtin_amdgcn_mfma_f32_16x16x32_bf16(af0, bf, acc[0][j], 0, 0, 0);
            acc[1][j] = __builtin_amdgcn_mfma_f32_16x16x32_bf16(af1, bf, acc[1][j], 0, 0, 0);
        }
    }
    float vals[2][4][4];
#pragma unroll
    for (int m = 0; m < 2; ++m)
#pragma unroll
        for (int j = 0; j < 4; ++j) {
            const int k = j * 16 + lr;
            const float bs = bias[k];
#pragma unroll
            for (int r = 0; r < 4; ++r) vals[m][j][r] = acc[m][j][r] + bs;
            const int lb = l0 + w * 32 + m * 16 + oct * 4;
            float4 st = make_float4(vals[m][j][0], vals[m][j][1], vals[m][j][2], vals[m][j][3]);
            *(float4*)(logitsT + ((size_t)b * NK + k) * NL + lb) = st;
        }
    // fused partial softmax stats for this 128-l chunk (32 slots per k)
    __shared__ float red[64][33];
    __shared__ float bm[64];
    const int slot = w * 8 + oct * 2;
#pragma unroll
    for (int m = 0; m < 2; ++m) {
        const int lbase = l0 + w * 32 + m * 16 + oct * 4;
#pragma unroll
        for (int j = 0; j < 4; ++j) {
            float vm = -1e30f;
#pragma unroll
            for (int r = 0; r < 4; ++r)
                if (lbase + r < len) vm = fmaxf(vm, vals[m][j][r]);
            red[j * 16 + lr][slot + m] = vm;
        }
    }
    __syncthreads();
    if (t < 64) {
        float m = -1e30f;
#pragma unroll
        for (int q = 0; q < 32; ++q) m = fmaxf(m, red[t][q]);
        bm[t] = m;
    }
    __syncthreads();
#pragma unroll
    for (int m = 0; m < 2; ++m) {
        const int lbase = l0 + w * 32 + m * 16 + oct * 4;
#pragma unroll
        for (int j = 0; j < 4; ++j) {
            const float mk = bm[j * 16 + lr];
            float sj = 0.f;
#pragma unroll
            for (int r = 0; r < 4; ++r)
                if (lbase + r < len) sj += __expf(vals[m][j][r] - mk);
            red[j * 16 + lr][slot + m] = sj;
        }
    }
    __syncthreads();
    if (t < 64) {
        float ssum = 0.f;
#pragma unroll
        for (int q = 0; q < 32; ++q) ssum += red[t][q];
        pmax[((size_t)b * 32 + chunk) * 64 + t] = bm[t];
        psum[((size_t)b * 32 + chunk) * 64 + t] = ssum;
    }
}

// ---------------- Kernel 2: combine chunk stats -> mbuf2 = m + ln(s) per (b,k)
__global__ void k_sm2(const float* __restrict__ pmax, const float* __restrict__ psum,
                      const int* __restrict__ lens,
                      float* __restrict__ mbuf2) {
    const int b = blockIdx.x;
    const int k = threadIdx.x;  // 64 threads
    const int nc = (lens[b] + 127) >> 7;
    float m = -1e30f;
    for (int c = 0; c < nc; ++c) m = fmaxf(m, pmax[((size_t)b * 32 + c) * 64 + k]);
    float s = 0.f;
    for (int c = 0; c < nc; ++c)
        s += psum[((size_t)b * 32 + c) * 64 + k] * __expf(pmax[((size_t)b * 32 + c) * 64 + k] - m);
    mbuf2[b * 64 + k] = m + logf(s);
}

// ---------------- Kernel 3: bf16-MFMA aggregation (exact-a x bf16-f)
// a split hi/lo in registers (a = aH+aL exact); f rounded to bf16 in LDS.
// acc += aH*fH + aL*fH == a*fH with each product exact in fp32 accum.
__global__ __launch_bounds__(256, 4) void k_aggregate(const float* __restrict__ feats,
                                                      const float* __restrict__ logitsT,
                                                      const int* __restrict__ lens,
                                                      const float* __restrict__ mbuf2,
                                                      float* __restrict__ pO) {
    const int bid = blockIdx.x;
    const int s  = bid & 3;
    const int dc = (bid >> 2) & 7;
    const int b  = bid >> 5;
    const int d0 = dc * DTILE;
    const int t = threadIdx.x;
    const int w = t >> 6;
    const int lane = t & 63;
    const int lr = lane & 15;
    const int oct = lane >> 4;
    const int len = lens[b];
    const int nT = (len + 63) >> 6;
    const int t0 = (nT * s) >> 2;
    const int t1 = (nT * (s + 1)) >> 2;

    __shared__ char fH[16 * 1024];   // 16 KB: fT[128 d][64 l] bf16, chunk-XOR swizzled

    const int kk = w * 16 + lr;                      // A m-row = k
    const float ms2k = mbuf2[b * 64 + kk];
    const float* lgrow = logitsT + ((size_t)b * NK + kk) * NL;

    // f-staging constants: thread owns rows lf0+{0..3} (x2 phases), cols c4..c4+3
    const int c4 = (t & 31) * 4;
    const int lf0 = (t >> 5) * 4;

    f32x4_t acc[8];
#pragma unroll
    for (int n = 0; n < 8; ++n) acc[n] = (f32x4_t){0.f, 0.f, 0.f, 0.f};

    float4 plg[4];       // [ks*2+h]: logits l-run for A frags
    float4 pf[2][4];     // [phase][row]: f rows

#define LOADT(tile_)                                                                     \
    {                                                                                    \
        const int lb_ = (tile_) * 64;                                                    \
        plg[0] = *(const float4*)(lgrow + lb_ + oct * 8);                                \
        plg[1] = *(const float4*)(lgrow + lb_ + oct * 8 + 4);                            \
        plg[2] = *(const float4*)(lgrow + lb_ + 32 + oct * 8);                           \
        plg[3] = *(const float4*)(lgrow + lb_ + 32 + oct * 8 + 4);                       \
        _Pragma("unroll")                                                                \
        for (int p_ = 0; p_ < 2; ++p_) {                                                 \
            _Pragma("unroll")                                                            \
            for (int i_ = 0; i_ < 4; ++i_)                                               \
                pf[p_][i_] = *(const float4*)(feats +                                    \
                    ((size_t)b * NL + lb_ + p_ * 32 + lf0 + i_) * ND + d0 + c4);         \
        }                                                                                \
    }

    if (t0 < t1) LOADT(t0);

    for (int tile = t0; tile < t1; ++tile) {
        const int l0 = tile * 64;
        // ---- build A fragments in registers from plg (current tile)
        bf16x8 afH[2], afL[2];
#pragma unroll
        for (int ks = 0; ks < 2; ++ks) {
#pragma unroll
            for (int h = 0; h < 2; ++h) {
                const float4 v = plg[ks * 2 + h];
                const int lbase = l0 + ks * 32 + oct * 8 + h * 4;
                float av[4];
                av[0] = (lbase + 0 < len) ? __expf(v.x - ms2k) : 0.f;
                av[1] = (lbase + 1 < len) ? __expf(v.y - ms2k) : 0.f;
                av[2] = (lbase + 2 < len) ? __expf(v.z - ms2k) : 0.f;
                av[3] = (lbase + 3 < len) ? __expf(v.w - ms2k) : 0.f;
#pragma unroll
                for (int c = 0; c < 4; ++c) {
                    const bf16_t hi = (bf16_t)av[c];
                    afH[ks][h * 4 + c] = hi;
                    afL[ks][h * 4 + c] = (bf16_t)(av[c] - (float)hi);
                }
            }
        }
        __syncthreads();   // all waves done reading fH of previous tile
        // ---- stage f^T (bf16 hi only) from pf: 4x4 register micro-transpose
#pragma unroll
        for (int p = 0; p < 2; ++p) {
            const int l4 = p * 32 + lf0;
#pragma unroll
            for (int j = 0; j < 4; ++j) {
                const int d = c4 + j;
                bf16x4 hi;
                hi[0] = (bf16_t)(&pf[p][0].x)[j];
                hi[1] = (bf16_t)(&pf[p][1].x)[j];
                hi[2] = (bf16_t)(&pf[p][2].x)[j];
                hi[3] = (bf16_t)(&pf[p][3].x)[j];
                const int chunk = (l4 >> 3) ^ ((d ^ (d >> 3)) & 7);
                const int off = d * 128 + (chunk << 4) + (l4 & 7) * 2;
                *(bf16x4*)(fH + off) = hi;
            }
        }
        // ---- T14: issue next tile's global loads (in flight across barrier + MFMA)
        if (tile + 1 < t1) LOADT(tile + 1);
        __syncthreads();   // fH ready
        // ---- MFMA: wave w owns k in [w*16, w*16+16); 8 n-tiles of d
#pragma unroll
        for (int ks = 0; ks < 2; ++ks) {
            const int cbase = ks * 4 + oct;  // chunk of contraction l = ks*32 + oct*8
#pragma unroll
            for (int n = 0; n < 8; ++n) {
                const int d = n * 16 + lr;
                const int foff = d * 128 + ((cbase ^ ((d ^ (d >> 3)) & 7)) << 4);
                const bf16x8 bfH = *(const bf16x8*)(fH + foff);
                acc[n] = __builtin_amdgcn_mfma_f32_16x16x32_bf16(afH[ks], bfH, acc[n], 0, 0, 0);
                acc[n] = __builtin_amdgcn_mfma_f32_16x16x32_bf16(afL[ks], bfH, acc[n], 0, 0, 0);
            }
        }
    }
#undef LOADT
    // write fp32 partials: pO[b][dc][s][k][DTILE]; C: row(m=k)=oct*4+r, col=lr
    float* po = pO + ((size_t)((b * 8 + dc) * S_SPLIT + s)) * (NK * DTILE);
#pragma unroll
    for (int n = 0; n < 8; ++n) {
#pragma unroll
        for (int r = 0; r < 4; ++r) {
            const int k = w * 16 + oct * 4 + r;
            po[k * DTILE + n * 16 + lr] = acc[n][r];
        }
    }
}

// ---------------- Kernel 4: sum S_SPLIT partials, subtract centroid, min over k
__global__ __launch_bounds__(128) void k_combine(const float* __restrict__ pO,
                                                 const float* __restrict__ centroids,
                                                 float* __restrict__ outun) {
    const int b = blockIdx.x >> 3;
    const int d = (blockIdx.x & 7) * 128 + threadIdx.x;  // 0..1023
    const int dc = d >> 7;
    const int dl = d & 127;
    const float* base = pO + ((size_t)(b * 8 + dc)) * S_SPLIT * NK * DTILE;
    float mn = 1e30f;
    for (int k = 0; k < NK; ++k) {
        float v = 0.f;
#pragma unroll
        for (int s = 0; s < S_SPLIT; ++s) v += base[(size_t)(s * NK + k) * DTILE + dl];
        v -= centroids[(size_t)k * ND + d];
        mn = fminf(mn, v);
    }
    outun[(size_t)b * ND + d] = mn;
}

// ---------------- Kernel 5: L2-normalize rows
__global__ __launch_bounds__(256) void k_norm(const float* __restrict__ outun,
                                              float* __restrict__ out) {
    const int b = blockIdx.x;
    const int t = threadIdx.x;
    float ss = 0.f;
    for (int d = t; d < ND; d += 256) {
        const float v = outun[(size_t)b * ND + d];
        ss += v * v;
    }
#pragma unroll
    for (int off = 32; off > 0; off >>= 1) ss += __shfl_down(ss, off);
    __shared__ float red[4];
    if ((t & 63) == 0) red[t >> 6] = ss;
    __syncthreads();
    const float tot = red[0] + red[1] + red[2] + red[3];
    const float inv = 1.0f / fmaxf(sqrtf(tot), 1e-12f);
    for (int d = t; d < ND; d += 256) out[(size_t)b * ND + d] = outun[(size_t)b * ND + d] * inv;
}

extern "C" void kernel_launch(void* const* d_in, const int* in_sizes, int n_in,
                              void* d_out, int out_size, void* d_ws, size_t ws_size,
                              hipStream_t stream) {
    const float* feats     = (const float*)d_in[0];
    const int*   lens      = (const int*)d_in[1];
    const float* W         = (const float*)d_in[2];
    const float* bias      = (const float*)d_in[3];
    const float* centroids = (const float*)d_in[4];
    float* out = (float*)d_out;

    char* ws = (char*)d_ws;
    size_t off = 0;
    bf16_t* Wb     = (bf16_t*)(ws + off); off += (size_t)NK * ND * sizeof(bf16_t);
    float* logitsT = (float*)(ws + off);  off += (size_t)NB * NL * NK * sizeof(float);
    float* pmax    = (float*)(ws + off);  off += (size_t)NB * 32 * NK * sizeof(float);
    float* psum    = (float*)(ws + off);  off += (size_t)NB * 32 * NK * sizeof(float);
    float* mbuf2   = (float*)(ws + off);  off += (size_t)NB * NK * sizeof(float);
    float* outun   = (float*)(ws + off);  off += (size_t)NB * ND * sizeof(float);
    float* pO      = (float*)(ws + off);  // 32*8*4*64*128*4 = 33.6 MB

    k_convw<<<NK * ND / 1024, 256, 0, stream>>>(W, Wb);
    k_logits<<<NB * (NL / 128), 256, 0, stream>>>(feats, Wb, bias, lens, logitsT, pmax, psum);
    k_sm2<<<NB, 64, 0, stream>>>(pmax, psum, lens, mbuf2);
    k_aggregate<<<NB * 8 * S_SPLIT, 256, 0, stream>>>(feats, logitsT, lens, mbuf2, pO);
    k_combine<<<NB * 8, 128, 0, stream>>>(pO, centroids, outun);
    k_norm<<<NB, 256, 0, stream>>>(outun, out);
}

// Round 8
// 281.999 us; speedup vs baseline: 3.5365x; 1.0091x over previous
//
#include <hip/hip_runtime.h>
#include <math.h>

#define NB 32
#define NL 4096
#define ND 1024
#define NK 64
#define DTILE 128
#define S_SPLIT 4

typedef __bf16 bf16_t;
typedef __bf16 bf16x8 __attribute__((ext_vector_type(8)));
typedef __bf16 bf16x4 __attribute__((ext_vector_type(4)));
typedef float f32x4_t __attribute__((ext_vector_type(4)));

// ---------------- Kernel 0: W fp32 -> bf16
__global__ __launch_bounds__(256) void k_convw(const float* __restrict__ W,
                                               bf16_t* __restrict__ Wb) {
    const int i = (blockIdx.x * 256 + threadIdx.x) * 4;
    const float4 v = *(const float4*)(W + i);
    bf16x4 o;
    o[0] = (bf16_t)v.x; o[1] = (bf16_t)v.y; o[2] = (bf16_t)v.z; o[3] = (bf16_t)v.w;
    *(bf16x4*)(Wb + i) = o;
}

// ---------------- Kernel 1: logits (bf16 MFMA), 64 l per wave, 256 l per block
// Writes logitsT[b][k][l] with float4 stores; fused per-256-l-chunk softmax stats.
// Verified conv: A lane(lr,oct): m=lr, c=oct*8+j; B: n=lr, c=oct*8+j;
// C: col(n)=lane&15, row(m)=oct*4+reg.
__global__ __launch_bounds__(256, 2) void k_logits(const float* __restrict__ feats,
                                                   const bf16_t* __restrict__ Wb,
                                                   const float* __restrict__ bias,
                                                   const int* __restrict__ lens,
                                                   float* __restrict__ logitsT,
                                                   float* __restrict__ pmax,
                                                   float* __restrict__ psum) {
    const int bid = blockIdx.x;
    const int b = bid >> 4;
    const int chunk = bid & 15;
    const int l0 = chunk << 8;       // 256 l per block
    const int len = lens[b];
    if (l0 >= len) return;   // rows >= len never read downstream
    const int t = threadIdx.x;
    const int w = t >> 6;
    const int lane = t & 63;
    const int lr = lane & 15;
    const int oct = lane >> 4;
    const int lw = l0 + w * 64;      // wave's l-base (4 m-tiles of 16)
    const float* fp = feats + ((size_t)b * NL + lw + lr) * ND + oct * 8;

    f32x4_t acc[4][4];  // [mt][j]
#pragma unroll
    for (int m = 0; m < 4; ++m)
#pragma unroll
        for (int j = 0; j < 4; ++j) acc[m][j] = (f32x4_t){0.f, 0.f, 0.f, 0.f};

#pragma unroll 2
    for (int kk = 0; kk < 32; ++kk) {
        const int d = kk * 32;
        bf16x8 af[4];
#pragma unroll
        for (int mt = 0; mt < 4; ++mt) {
            const float4 a0 = *(const float4*)(fp + (size_t)mt * 16 * ND + d);
            const float4 a1 = *(const float4*)(fp + (size_t)mt * 16 * ND + d + 4);
            af[mt][0] = (bf16_t)a0.x; af[mt][1] = (bf16_t)a0.y;
            af[mt][2] = (bf16_t)a0.z; af[mt][3] = (bf16_t)a0.w;
            af[mt][4] = (bf16_t)a1.x; af[mt][5] = (bf16_t)a1.y;
            af[mt][6] = (bf16_t)a1.z; af[mt][7] = (bf16_t)a1.w;
        }
#pragma unroll
        for (int j = 0; j < 4; ++j) {
            const bf16x8 bf = *(const bf16x8*)(Wb + (size_t)(j * 16 + lr) * ND + d + oct * 8);
#pragma unroll
            for (int mt = 0; mt < 4; ++mt)
                acc[mt][j] = __builtin_amdgcn_mfma_f32_16x16x32_bf16(af[mt], bf, acc[mt][j], 0, 0, 0);
        }
    }
    float vals[4][4][4];
#pragma unroll
    for (int mt = 0; mt < 4; ++mt)
#pragma unroll
        for (int j = 0; j < 4; ++j) {
            const int k = j * 16 + lr;
            const float bs = bias[k];
#pragma unroll
            for (int r = 0; r < 4; ++r) vals[mt][j][r] = acc[mt][j][r] + bs;
            const int lb = lw + mt * 16 + oct * 4;
            float4 st = make_float4(vals[mt][j][0], vals[mt][j][1], vals[mt][j][2], vals[mt][j][3]);
            *(float4*)(logitsT + ((size_t)b * NK + k) * NL + lb) = st;
        }
    // fused partial softmax stats for this 256-l chunk (16 slots per k)
    __shared__ float red[64][17];
    __shared__ float bm[64];
    const int slot = w * 4 + oct;
#pragma unroll
    for (int j = 0; j < 4; ++j) {
        float vm = -1e30f;
#pragma unroll
        for (int mt = 0; mt < 4; ++mt) {
            const int lbase = lw + mt * 16 + oct * 4;
#pragma unroll
            for (int r = 0; r < 4; ++r)
                if (lbase + r < len) vm = fmaxf(vm, vals[mt][j][r]);
        }
        red[j * 16 + lr][slot] = vm;
    }
    __syncthreads();
    if (t < 64) {
        float m = -1e30f;
#pragma unroll
        for (int q = 0; q < 16; ++q) m = fmaxf(m, red[t][q]);
        bm[t] = m;
    }
    __syncthreads();
#pragma unroll
    for (int j = 0; j < 4; ++j) {
        const float mk = bm[j * 16 + lr];
        float sj = 0.f;
#pragma unroll
        for (int mt = 0; mt < 4; ++mt) {
            const int lbase = lw + mt * 16 + oct * 4;
#pragma unroll
            for (int r = 0; r < 4; ++r)
                if (lbase + r < len) sj += __expf(vals[mt][j][r] - mk);
        }
        red[j * 16 + lr][slot] = sj;
    }
    __syncthreads();
    if (t < 64) {
        float ssum = 0.f;
#pragma unroll
        for (int q = 0; q < 16; ++q) ssum += red[t][q];
        pmax[((size_t)b * 16 + chunk) * 64 + t] = bm[t];
        psum[((size_t)b * 16 + chunk) * 64 + t] = ssum;
    }
}

// ---------------- Kernel 2: combine chunk stats -> mbuf2 = m + ln(s) per (b,k)
__global__ void k_sm2(const float* __restrict__ pmax, const float* __restrict__ psum,
                      const int* __restrict__ lens,
                      float* __restrict__ mbuf2) {
    const int b = blockIdx.x;
    const int k = threadIdx.x;  // 64 threads
    const int nc = (lens[b] + 255) >> 8;
    float m = -1e30f;
    for (int c = 0; c < nc; ++c) m = fmaxf(m, pmax[((size_t)b * 16 + c) * 64 + k]);
    float s = 0.f;
    for (int c = 0; c < nc; ++c)
        s += psum[((size_t)b * 16 + c) * 64 + k] * __expf(pmax[((size_t)b * 16 + c) * 64 + k] - m);
    mbuf2[b * 64 + k] = m + logf(s);
}

// ---------------- Kernel 3: bf16-MFMA aggregation (exact-a x bf16-f)
// Wave partition: w -> (kh = w&1: 32 k) x (dh = w>>1: 64 d); B-frags shared
// across 2 m-tiles (halves per-CU LDS reads vs k-only split).
__global__ __launch_bounds__(256, 3) void k_aggregate(const float* __restrict__ feats,
                                                      const float* __restrict__ logitsT,
                                                      const int* __restrict__ lens,
                                                      const float* __restrict__ mbuf2,
                                                      float* __restrict__ pO) {
    const int bid = blockIdx.x;
    const int s  = bid & 3;
    const int dc = (bid >> 2) & 7;
    const int b  = bid >> 5;
    const int d0 = dc * DTILE;
    const int t = threadIdx.x;
    const int kh = (t >> 6) & 1;
    const int dh = t >> 7;
    const int lane = t & 63;
    const int lr = lane & 15;
    const int oct = lane >> 4;
    const int len = lens[b];
    const int nT = (len + 63) >> 6;
    const int t0 = (nT * s) >> 2;
    const int t1 = (nT * (s + 1)) >> 2;

    __shared__ char fH[16 * 1024];   // fT[128 d][64 l] bf16, chunk-XOR swizzled

    const int kk0 = kh * 32 + lr;    // A m-row (k) for mt=0; mt=1 adds 16
    const float ms0 = mbuf2[b * 64 + kk0];
    const float ms1 = mbuf2[b * 64 + kk0 + 16];
    const float* lg0 = logitsT + ((size_t)b * NK + kk0) * NL;
    const float* lg1 = lg0 + (size_t)16 * NL;

    // f-staging constants: thread owns rows lf0+{0..3} (x2 phases), cols c4..c4+3
    const int c4 = (t & 31) * 4;
    const int lf0 = (t >> 5) * 4;

    f32x4_t acc[2][4];  // [mt][n]
#pragma unroll
    for (int m = 0; m < 2; ++m)
#pragma unroll
        for (int n = 0; n < 4; ++n) acc[m][n] = (f32x4_t){0.f, 0.f, 0.f, 0.f};

    float4 pf[2][4];     // [phase][row]: prefetched f rows (T14)

#define LOADF(tile_)                                                                     \
    {                                                                                    \
        const int lb_ = (tile_) * 64;                                                    \
        _Pragma("unroll")                                                                \
        for (int p_ = 0; p_ < 2; ++p_) {                                                 \
            _Pragma("unroll")                                                            \
            for (int i_ = 0; i_ < 4; ++i_)                                               \
                pf[p_][i_] = *(const float4*)(feats +                                    \
                    ((size_t)b * NL + lb_ + p_ * 32 + lf0 + i_) * ND + d0 + c4);         \
        }                                                                                \
    }

    if (t0 < t1) LOADF(t0);

    for (int tile = t0; tile < t1; ++tile) {
        const int l0 = tile * 64;
        // ---- load this tile's logits runs + build A fragments in registers
        bf16x8 afH[2][2], afL[2][2];   // [mt][ks]
#pragma unroll
        for (int mt = 0; mt < 2; ++mt) {
            const float* lg = mt ? lg1 : lg0;
            const float msk = mt ? ms1 : ms0;
            float4 g[4];
            g[0] = *(const float4*)(lg + l0 + oct * 8);
            g[1] = *(const float4*)(lg + l0 + oct * 8 + 4);
            g[2] = *(const float4*)(lg + l0 + 32 + oct * 8);
            g[3] = *(const float4*)(lg + l0 + 32 + oct * 8 + 4);
#pragma unroll
            for (int ks = 0; ks < 2; ++ks) {
#pragma unroll
                for (int h = 0; h < 2; ++h) {
                    const float4 v = g[ks * 2 + h];
                    const int lbase = l0 + ks * 32 + oct * 8 + h * 4;
                    float av[4];
                    av[0] = (lbase + 0 < len) ? __expf(v.x - msk) : 0.f;
                    av[1] = (lbase + 1 < len) ? __expf(v.y - msk) : 0.f;
                    av[2] = (lbase + 2 < len) ? __expf(v.z - msk) : 0.f;
                    av[3] = (lbase + 3 < len) ? __expf(v.w - msk) : 0.f;
#pragma unroll
                    for (int c = 0; c < 4; ++c) {
                        const bf16_t hi = (bf16_t)av[c];
                        afH[mt][ks][h * 4 + c] = hi;
                        afL[mt][ks][h * 4 + c] = (bf16_t)(av[c] - (float)hi);
                    }
                }
            }
        }
        __syncthreads();   // all waves done reading fH of previous tile
        // ---- stage f^T (bf16) from pf: 4x4 register micro-transpose
#pragma unroll
        for (int p = 0; p < 2; ++p) {
            const int l4 = p * 32 + lf0;
#pragma unroll
            for (int j = 0; j < 4; ++j) {
                const int d = c4 + j;
                bf16x4 hi;
                hi[0] = (bf16_t)(&pf[p][0].x)[j];
                hi[1] = (bf16_t)(&pf[p][1].x)[j];
                hi[2] = (bf16_t)(&pf[p][2].x)[j];
                hi[3] = (bf16_t)(&pf[p][3].x)[j];
                const int chunk = (l4 >> 3) ^ ((d ^ (d >> 3)) & 7);
                const int off = d * 128 + (chunk << 4) + (l4 & 7) * 2;
                *(bf16x4*)(fH + off) = hi;
            }
        }
        // ---- T14: issue next tile's f loads (in flight across barrier + MFMA)
        if (tile + 1 < t1) LOADF(tile + 1);
        __syncthreads();   // fH ready
        // ---- MFMA: wave owns k in [kh*32, +32), d in [dh*64, +64)
#pragma unroll
        for (int ks = 0; ks < 2; ++ks) {
            const int cbase = ks * 4 + oct;  // chunk of contraction l = ks*32 + oct*8
            bf16x8 bfv[4];
#pragma unroll
            for (int n = 0; n < 4; ++n) {
                const int d = dh * 64 + n * 16 + lr;
                const int foff = d * 128 + ((cbase ^ ((d ^ (d >> 3)) & 7)) << 4);
                bfv[n] = *(const bf16x8*)(fH + foff);
            }
#pragma unroll
            for (int mt = 0; mt < 2; ++mt)
#pragma unroll
                for (int n = 0; n < 4; ++n) {
                    acc[mt][n] = __builtin_amdgcn_mfma_f32_16x16x32_bf16(afH[mt][ks], bfv[n], acc[mt][n], 0, 0, 0);
                    acc[mt][n] = __builtin_amdgcn_mfma_f32_16x16x32_bf16(afL[mt][ks], bfv[n], acc[mt][n], 0, 0, 0);
                }
        }
    }
#undef LOADF
    // write fp32 partials: pO[b][dc][s][k][DTILE]; C: row(m=k)=oct*4+r, col=lr
    float* po = pO + ((size_t)((b * 8 + dc) * S_SPLIT + s)) * (NK * DTILE);
#pragma unroll
    for (int mt = 0; mt < 2; ++mt)
#pragma unroll
        for (int n = 0; n < 4; ++n) {
#pragma unroll
            for (int r = 0; r < 4; ++r) {
                const int k = kh * 32 + mt * 16 + oct * 4 + r;
                po[k * DTILE + dh * 64 + n * 16 + lr] = acc[mt][n][r];
            }
        }
}

// ---------------- Kernel 4: sum S_SPLIT partials, subtract centroid, min over k
__global__ __launch_bounds__(128) void k_combine(const float* __restrict__ pO,
                                                 const float* __restrict__ centroids,
                                                 float* __restrict__ outun) {
    const int b = blockIdx.x >> 3;
    const int d = (blockIdx.x & 7) * 128 + threadIdx.x;  // 0..1023
    const int dc = d >> 7;
    const int dl = d & 127;
    const float* base = pO + ((size_t)(b * 8 + dc)) * S_SPLIT * NK * DTILE;
    float mn = 1e30f;
    for (int k = 0; k < NK; ++k) {
        float v = 0.f;
#pragma unroll
        for (int s = 0; s < S_SPLIT; ++s) v += base[(size_t)(s * NK + k) * DTILE + dl];
        v -= centroids[(size_t)k * ND + d];
        mn = fminf(mn, v);
    }
    outun[(size_t)b * ND + d] = mn;
}

// ---------------- Kernel 5: L2-normalize rows
__global__ __launch_bounds__(256) void k_norm(const float* __restrict__ outun,
                                              float* __restrict__ out) {
    const int b = blockIdx.x;
    const int t = threadIdx.x;
    float ss = 0.f;
    for (int d = t; d < ND; d += 256) {
        const float v = outun[(size_t)b * ND + d];
        ss += v * v;
    }
#pragma unroll
    for (int off = 32; off > 0; off >>= 1) ss += __shfl_down(ss, off);
    __shared__ float red[4];
    if ((t & 63) == 0) red[t >> 6] = ss;
    __syncthreads();
    const float tot = red[0] + red[1] + red[2] + red[3];
    const float inv = 1.0f / fmaxf(sqrtf(tot), 1e-12f);
    for (int d = t; d < ND; d += 256) out[(size_t)b * ND + d] = outun[(size_t)b * ND + d] * inv;
}

extern "C" void kernel_launch(void* const* d_in, const int* in_sizes, int n_in,
                              void* d_out, int out_size, void* d_ws, size_t ws_size,
                              hipStream_t stream) {
    const float* feats     = (const float*)d_in[0];
    const int*   lens      = (const int*)d_in[1];
    const float* W         = (const float*)d_in[2];
    const float* bias      = (const float*)d_in[3];
    const float* centroids = (const float*)d_in[4];
    float* out = (float*)d_out;

    char* ws = (char*)d_ws;
    size_t off = 0;
    bf16_t* Wb     = (bf16_t*)(ws + off); off += (size_t)NK * ND * sizeof(bf16_t);
    float* logitsT = (float*)(ws + off);  off += (size_t)NB * NL * NK * sizeof(float);
    float* pmax    = (float*)(ws + off);  off += (size_t)NB * 16 * NK * sizeof(float);
    float* psum    = (float*)(ws + off);  off += (size_t)NB * 16 * NK * sizeof(float);
    float* mbuf2   = (float*)(ws + off);  off += (size_t)NB * NK * sizeof(float);
    float* outun   = (float*)(ws + off);  off += (size_t)NB * ND * sizeof(float);
    float* pO      = (float*)(ws + off);  // 32*8*4*64*128*4 = 33.6 MB

    k_convw<<<NK * ND / 1024, 256, 0, stream>>>(W, Wb);
    k_logits<<<NB * (NL / 256), 256, 0, stream>>>(feats, Wb, bias, lens, logitsT, pmax, psum);
    k_sm2<<<NB, 64, 0, stream>>>(pmax, psum, lens, mbuf2);
    k_aggregate<<<NB * 8 * S_SPLIT, 256, 0, stream>>>(feats, logitsT, lens, mbuf2, pO);
    k_combine<<<NB * 8, 128, 0, stream>>>(pO, centroids, outun);
    k_norm<<<NB, 256, 0, stream>>>(outun, out);
}